// Round 2
// baseline (101.389 us; speedup 1.0000x reference)
//
#include <hip/hip_runtime.h>
#include <hip/hip_bf16.h>
#include <hip/hip_fp16.h>
#include <math.h>

// B=8, CIN=COUT=128, H=W=Ho=Wo=64, K=9, stride=pad=dil=1, EPS=1e-4.
//
// Pipeline (2 launches):
//   prep_k  : blocks 0..511  -> xt[b][h][w][c] bf16 transpose, XCD-aligned
//             blocks 512..543 -> weight norm -> bf16 A-fragment order
//                                wb[k][c/8][cout][c%8]
//   dconv_k : 512 blocks x 512 thr (8 waves), block = 64 pixels x 128 couts.
//             NEW this round: wave tile re-decomposed 64pix x 16cout ->
//             32pix x 32cout (2x2 register blocking). Halves the dominant
//             LDS pipe traffic (B-frag ds_read_b128 16 -> 8 per wave-tap;
//             each B-frag feeds 2 cout tiles from regs). Tap geometry packed
//             into ONE 16-B record (4x fp16 corner weights + 4x u16 corner
//             indices): geometry 4 -> 2 LDS reads per wave-tap.

typedef __attribute__((ext_vector_type(8))) short short8;   // 8 bf16 = 4 VGPRs
typedef __attribute__((ext_vector_type(4))) float floatx4;
typedef __attribute__((ext_vector_type(2))) float floatx2;

static __device__ __forceinline__ unsigned int f2bf(float f) {
    unsigned int u = __float_as_uint(f);
    u += 0x7fffu + ((u >> 16) & 1u);          // round-to-nearest-even
    return u >> 16;
}
// hw v_cvt_pk_bf16_f32 pack
static __device__ __forceinline__ unsigned int packbf2(float lo, float hi) {
    __hip_bfloat162 h = __float22bfloat162_rn(make_float2(lo, hi));
    unsigned int u;
    __builtin_memcpy(&u, &h, 4);
    return u;
}
// unpack 2 bf16 (one dword) -> float2 {lo, hi}
static __device__ __forceinline__ floatx2 bf2f2(unsigned int w) {
    floatx2 r;
    r.x = __uint_as_float(w << 16);
    r.y = __uint_as_float(w & 0xffff0000u);
    return r;
}

// Fused transpose (blocks 0..511, XCD-aligned) + weight-norm (512..543)
__global__ void prep_k(const float* __restrict__ x, const float* __restrict__ w,
                       unsigned int* __restrict__ xt32, unsigned short* __restrict__ wb) {
    __shared__ float lds[128 * 65];
    const int tid = threadIdx.x;        // 256

    if (blockIdx.x < 512) {
        const int b = blockIdx.x & 7, h = (blockIdx.x >> 3) & 63;
        const float* xp = x + (b * 128 * 64 + h) * 64;
        #pragma unroll 4
        for (int i = 0; i < 32; i++) {
            const int c = i * 4 + (tid >> 6);
            const int ww = tid & 63;
            lds[c * 65 + ww] = xp[c * 4096 + ww];
        }
        __syncthreads();
        unsigned int* xo = xt32 + (b * 64 + h) * 4096;   // [b][h][w][c/2]
        #pragma unroll 4
        for (int i = 0; i < 16; i++) {
            const int flat2 = i * 256 + tid;             // w*64 + cpair
            const int ww = flat2 >> 6, cp = flat2 & 63;
            xo[flat2] = packbf2(lds[(2 * cp) * 65 + ww], lds[(2 * cp + 1) * 65 + ww]);
        }
    } else {
        // weight norm: wave per cout o; lane holds c=2*lane, 2*lane+1
        const int o = (blockIdx.x - 512) * 4 + (tid >> 6);
        const int lane = tid & 63;
        const float* wo = w + o * 1152;                  // [c][k]
        float v[18];
        #pragma unroll
        for (int i = 0; i < 18; i++) v[i] = wo[lane * 18 + i];
        float s[9];
        #pragma unroll
        for (int k = 0; k < 9; k++) s[k] = v[k] * v[k] + v[9 + k] * v[9 + k];
        #pragma unroll
        for (int d = 32; d >= 1; d >>= 1) {
            #pragma unroll
            for (int k = 0; k < 9; k++) s[k] += __shfl_xor(s[k], d, 64);
        }
        const int c0 = 2 * lane, c1 = c0 + 1;
        #pragma unroll
        for (int k = 0; k < 9; k++) {
            const float inv = 1.0f / (3.0f * sqrtf(s[k] + 0.0128f));   // 128*EPS
            wb[((k * 16 + (c0 >> 3)) * 128 + o) * 8 + (c0 & 7)] = (unsigned short)f2bf(v[k] * inv);
            wb[((k * 16 + (c1 >> 3)) * 128 + o) * 8 + (c1 & 7)] = (unsigned short)f2bf(v[9 + k] * inv);
        }
    }
}

// packed-fp32 bilinear blend of one bf16 pair (dword) from 4 corners
static __device__ __forceinline__ unsigned int bl1(const float4 w,
                                                   unsigned int r0, unsigned int r1,
                                                   unsigned int r2, unsigned int r3) {
    floatx2 a = bf2f2(r0) * w.x;
    a += bf2f2(r1) * w.y;
    a += bf2f2(r2) * w.z;
    a += bf2f2(r3) * w.w;
    return packbf2(a.x, a.y);
}

static __device__ __forceinline__ uint4 combine4(const float4 wvv,
                                                 const uint4 r0, const uint4 r1,
                                                 const uint4 r2, const uint4 r3) {
    uint4 pk;
    pk.x = bl1(wvv, r0.x, r1.x, r2.x, r3.x);
    pk.y = bl1(wvv, r0.y, r1.y, r2.y, r3.y);
    pk.z = bl1(wvv, r0.z, r1.z, r2.z, r3.z);
    pk.w = bl1(wvv, r0.w, r1.w, r2.w, r3.w);
    return pk;
}

// expand packed 16-B tap record -> corner weights + corner elem offsets
static __device__ __forceinline__ void rec_expand(const uint4 rec, float4& wvv, int4& iv) {
    const float2 w01 = __half22float2(*reinterpret_cast<const __half2*>(&rec.x));
    const float2 w23 = __half22float2(*reinterpret_cast<const __half2*>(&rec.y));
    wvv = make_float4(w01.x, w01.y, w23.x, w23.y);
    iv = make_int4((int)(rec.z & 0xffffu) << 7, (int)(rec.z >> 16) << 7,
                   (int)(rec.w & 0xffffu) << 7, (int)(rec.w >> 16) << 7);
}

__global__ __launch_bounds__(512, 4) void dconv_k(
    const unsigned short* __restrict__ xt, const float* __restrict__ off,
    const unsigned short* __restrict__ wb, float* __restrict__ out)
{
    // LDS: 9216 (packed taps) + 2*16640*2B (cols) = 42496 B -> 2 blocks/CU
    __shared__ alignas(16) uint4 tapG[576];                   // [k][p] packed geometry
    __shared__ alignas(16) unsigned short colsS[2][16 * 520]; // [buf][c/8][64pix][8], +8el pad

    const int idx = blockIdx.x;
    const int b = idx & 7;                 // XCD-local batch
    const int ho = (idx >> 3) & 63;
    const int tid = threadIdx.x;           // 512

    // ---- packed tap geometry: 576 = 9 taps x 64 pixels, 16 B each ----
    for (int t = tid; t < 576; t += 512) {
        const int k = t >> 6, p = t & 63;
        const int oidx = ((b * 18 + 2 * k) * 64 + ho) * 64 + p;
        const float offy = off[oidx];
        const float offx = off[oidx + 4096];
        const float py = (float)(ho - 1 + (k / 3)) + offy;
        const float px = (float)(p - 1 + (k % 3)) + offx;
        const float y0f = floorf(py), x0f = floorf(px);
        const float ly = py - y0f, lx = px - x0f;
        const int y0 = (int)y0f, x0 = (int)x0f;
        const int y1 = y0 + 1, x1 = x0 + 1;
        const float fy0 = (y0 >= 0 && y0 < 64) ? (1.0f - ly) : 0.0f;
        const float fy1 = (y1 >= 0 && y1 < 64) ? ly : 0.0f;
        const float fx0 = (x0 >= 0 && x0 < 64) ? (1.0f - lx) : 0.0f;
        const float fx1 = (x1 >= 0 && x1 < 64) ? lx : 0.0f;
        const int yc0 = min(max(y0, 0), 63), yc1 = min(max(y1, 0), 63);
        const int xc0 = min(max(x0, 0), 63), xc1 = min(max(x1, 0), 63);
        const __half2 a01 = __float22half2_rn(make_float2(fy0 * fx0, fy0 * fx1));
        const __half2 a23 = __float22half2_rn(make_float2(fy1 * fx0, fy1 * fx1));
        uint4 pk;
        __builtin_memcpy(&pk.x, &a01, 4);
        __builtin_memcpy(&pk.y, &a23, 4);
        pk.z = (unsigned int)(yc0 * 64 + xc0) | ((unsigned int)(yc0 * 64 + xc1) << 16);
        pk.w = (unsigned int)(yc1 * 64 + xc0) | ((unsigned int)(yc1 * 64 + xc1) << 16);
        tapG[t] = pk;
    }
    __syncthreads();

    const int lane = tid & 63, wv = tid >> 6;   // 8 waves
    const int quad = lane >> 4, l16 = lane & 15;
    const int g = tid & 15, p0 = tid >> 4;      // gather cell: c-octet g, pixel p0 (0..31)
    const unsigned short* xb = xt + b * (64 * 64 * 128);
    const int ph = wv & 1,  cq = wv >> 1;       // wave = 32 pixels x 32 couts
    const int pbase = ph * 32;
    const int obase = cq * 32;

    floatx4 acc[4];                             // [t(pix-tile)*2 + n(cout-tile)]
    #pragma unroll
    for (int t = 0; t < 4; t++) acc[t] = (floatx4)0.0f;

    // ---- prologue: gather tap 0 (each thread: pixels p0, p0+32) ----
    #pragma unroll
    for (int i = 0; i < 2; i++) {
        const int p = p0 + i * 32;
        float4 wvv; int4 iv;
        rec_expand(tapG[p], wvv, iv);           // broadcast across the 16 g-threads
        const uint4 r0 = *(const uint4*)(xb + iv.x + g * 8);
        const uint4 r1 = *(const uint4*)(xb + iv.y + g * 8);
        const uint4 r2 = *(const uint4*)(xb + iv.z + g * 8);
        const uint4 r3 = *(const uint4*)(xb + iv.w + g * 8);
        *(uint4*)&colsS[0][g * 520 + p * 8] = combine4(wvv, r0, r1, r2, r3);
    }
    __syncthreads();

    // ---- tap loop: one barrier per tap ----
    for (int k = 0; k < 9; k++) {
        const int cur = k & 1;

        // A-fragments (32-cout slice, 2x per k-step) issued first: 8 x 16B L2 loads
        const unsigned short* wk = wb + k * 16384;
        short8 a[8];                            // [q*2 + n]
        #pragma unroll
        for (int q = 0; q < 4; q++) {
            const int cgrp = q * 4 + quad;
            #pragma unroll
            for (int n = 0; n < 2; n++)
                a[q * 2 + n] = *(const short8*)(wk + (cgrp * 128 + obase + n * 16 + l16) * 8);
        }

        // corner prefetch for tap k+1 (8 independent dwordx4)
        uint4 r[2][4];
        float4 wvv[2];
        if (k < 8) {
            #pragma unroll
            for (int i = 0; i < 2; i++) {
                const int p = p0 + i * 32;
                int4 iv;
                rec_expand(tapG[(k + 1) * 64 + p], wvv[i], iv);
                r[i][0] = *(const uint4*)(xb + iv.x + g * 8);
                r[i][1] = *(const uint4*)(xb + iv.y + g * 8);
                r[i][2] = *(const uint4*)(xb + iv.z + g * 8);
                r[i][3] = *(const uint4*)(xb + iv.w + g * 8);
            }
        }

        // MFMA: 16 per wave per tap (4 k-steps x 2 pix-tiles x 2 cout-tiles),
        // only 8 B-frag LDS reads (each feeds both cout tiles from registers)
        #pragma unroll
        for (int q = 0; q < 4; q++) {
            const int cgrp = q * 4 + quad;
            const short8 bf0 = *(const short8*)&colsS[cur][cgrp * 520 + (pbase + l16) * 8];
            const short8 bf1 = *(const short8*)&colsS[cur][cgrp * 520 + (pbase + 16 + l16) * 8];
            acc[0] = __builtin_amdgcn_mfma_f32_16x16x32_bf16(a[q * 2 + 0], bf0, acc[0], 0, 0, 0);
            acc[1] = __builtin_amdgcn_mfma_f32_16x16x32_bf16(a[q * 2 + 1], bf0, acc[1], 0, 0, 0);
            acc[2] = __builtin_amdgcn_mfma_f32_16x16x32_bf16(a[q * 2 + 0], bf1, acc[2], 0, 0, 0);
            acc[3] = __builtin_amdgcn_mfma_f32_16x16x32_bf16(a[q * 2 + 1], bf1, acc[3], 0, 0, 0);
        }

        // combine + write tap k+1 into the other buffer, single barrier
        if (k < 8) {
            #pragma unroll
            for (int i = 0; i < 2; i++) {
                const int p = p0 + i * 32;
                *(uint4*)&colsS[cur ^ 1][g * 520 + p * 8] =
                    combine4(wvv[i], r[i][0], r[i][1], r[i][2], r[i][3]);
            }
            __syncthreads();
        }
    }

    // ---- epilogue: C/D col(=pixel)=lane&15, row(=cout)=quad*4+reg; NT stores ----
    float* ob = out + b * 128 * 4096 + ho * 64;
    #pragma unroll
    for (int t = 0; t < 2; t++) {
        const int pix = pbase + t * 16 + l16;
        #pragma unroll
        for (int n = 0; n < 2; n++) {
            #pragma unroll
            for (int r2 = 0; r2 < 4; r2++) {
                __builtin_nontemporal_store(acc[t * 2 + n][r2],
                    &ob[(obase + n * 16 + quad * 4 + r2) * 4096 + pix]);
            }
        }
    }
}

extern "C" void kernel_launch(void* const* d_in, const int* in_sizes, int n_in,
                              void* d_out, int out_size, void* d_ws, size_t ws_size,
                              hipStream_t stream) {
    const float* x   = (const float*)d_in[0];   // [8][128][64][64]
    const float* off = (const float*)d_in[1];   // [8][18][64][64]
    const float* w   = (const float*)d_in[2];   // [128][128][3][3]
    float* out = (float*)d_out;                 // [8][128][64][64]

    unsigned short* xt = (unsigned short*)d_ws;          // 4,194,304 bf16 = 8 MiB
    unsigned short* wbuf = xt + 8 * 64 * 64 * 128;       // 147,456 bf16

    hipLaunchKernelGGL(prep_k,  dim3(544), dim3(256), 0, stream,
                       x, w, (unsigned int*)xt, wbuf);
    hipLaunchKernelGGL(dconv_k, dim3(512), dim3(512), 0, stream, xt, off, wbuf, out);
}

// Round 3
// 99.031 us; speedup vs baseline: 1.0238x; 1.0238x over previous
//
#include <hip/hip_runtime.h>
#include <hip/hip_bf16.h>
#include <hip/hip_fp16.h>
#include <math.h>

// B=8, CIN=COUT=128, H=W=Ho=Wo=64, K=9, stride=pad=dil=1, EPS=1e-4.
//
// Pipeline (2 launches):
//   prep_k  : blocks 0..511  -> xt[b][h][w][c] bf16 transpose, XCD-aligned
//             blocks 512..543 -> weight norm -> bf16 A-fragment order
//                                wb[k][c/8][cout][c%8]
//   dconv_k : 512 blocks x 512 thr (8 waves), block = 64 pixels x 128 couts.
//             Wave tile 32pix x 32cout (2x2 register blocking).
//             NEW this round: software-pipelined gathers with a FULL-TAP
//             distance (gathers for tap k+2 issued at tap k, combined at
//             tap k+1) + raw s_barrier with lgkmcnt-only wait, so the
//             scattered L2 gather loads stay IN FLIGHT across the barrier
//             (no __syncthreads vmcnt(0) drain). Attacks the per-tap
//             exposed-latency serialization that rounds 1-2 proved is the
//             bottleneck (no pipe >40% busy).

typedef __attribute__((ext_vector_type(8))) short short8;   // 8 bf16 = 4 VGPRs
typedef __attribute__((ext_vector_type(4))) float floatx4;
typedef __attribute__((ext_vector_type(2))) float floatx2;

static __device__ __forceinline__ unsigned int f2bf(float f) {
    unsigned int u = __float_as_uint(f);
    u += 0x7fffu + ((u >> 16) & 1u);          // round-to-nearest-even
    return u >> 16;
}
// hw v_cvt_pk_bf16_f32 pack
static __device__ __forceinline__ unsigned int packbf2(float lo, float hi) {
    __hip_bfloat162 h = __float22bfloat162_rn(make_float2(lo, hi));
    unsigned int u;
    __builtin_memcpy(&u, &h, 4);
    return u;
}
// unpack 2 bf16 (one dword) -> float2 {lo, hi}
static __device__ __forceinline__ floatx2 bf2f2(unsigned int w) {
    floatx2 r;
    r.x = __uint_as_float(w << 16);
    r.y = __uint_as_float(w & 0xffff0000u);
    return r;
}

// Fused transpose (blocks 0..511, XCD-aligned) + weight-norm (512..543)
__global__ void prep_k(const float* __restrict__ x, const float* __restrict__ w,
                       unsigned int* __restrict__ xt32, unsigned short* __restrict__ wb) {
    __shared__ float lds[128 * 65];
    const int tid = threadIdx.x;        // 256

    if (blockIdx.x < 512) {
        const int b = blockIdx.x & 7, h = (blockIdx.x >> 3) & 63;
        const float* xp = x + (b * 128 * 64 + h) * 64;
        #pragma unroll 4
        for (int i = 0; i < 32; i++) {
            const int c = i * 4 + (tid >> 6);
            const int ww = tid & 63;
            lds[c * 65 + ww] = xp[c * 4096 + ww];
        }
        __syncthreads();
        unsigned int* xo = xt32 + (b * 64 + h) * 4096;   // [b][h][w][c/2]
        #pragma unroll 4
        for (int i = 0; i < 16; i++) {
            const int flat2 = i * 256 + tid;             // w*64 + cpair
            const int ww = flat2 >> 6, cp = flat2 & 63;
            xo[flat2] = packbf2(lds[(2 * cp) * 65 + ww], lds[(2 * cp + 1) * 65 + ww]);
        }
    } else {
        // weight norm: wave per cout o; lane holds c=2*lane, 2*lane+1
        const int o = (blockIdx.x - 512) * 4 + (tid >> 6);
        const int lane = tid & 63;
        const float* wo = w + o * 1152;                  // [c][k]
        float v[18];
        #pragma unroll
        for (int i = 0; i < 18; i++) v[i] = wo[lane * 18 + i];
        float s[9];
        #pragma unroll
        for (int k = 0; k < 9; k++) s[k] = v[k] * v[k] + v[9 + k] * v[9 + k];
        #pragma unroll
        for (int d = 32; d >= 1; d >>= 1) {
            #pragma unroll
            for (int k = 0; k < 9; k++) s[k] += __shfl_xor(s[k], d, 64);
        }
        const int c0 = 2 * lane, c1 = c0 + 1;
        #pragma unroll
        for (int k = 0; k < 9; k++) {
            const float inv = 1.0f / (3.0f * sqrtf(s[k] + 0.0128f));   // 128*EPS
            wb[((k * 16 + (c0 >> 3)) * 128 + o) * 8 + (c0 & 7)] = (unsigned short)f2bf(v[k] * inv);
            wb[((k * 16 + (c1 >> 3)) * 128 + o) * 8 + (c1 & 7)] = (unsigned short)f2bf(v[9 + k] * inv);
        }
    }
}

// packed-fp32 bilinear blend of one bf16 pair (dword) from 4 corners
static __device__ __forceinline__ unsigned int bl1(const float4 w,
                                                   unsigned int r0, unsigned int r1,
                                                   unsigned int r2, unsigned int r3) {
    floatx2 a = bf2f2(r0) * w.x;
    a += bf2f2(r1) * w.y;
    a += bf2f2(r2) * w.z;
    a += bf2f2(r3) * w.w;
    return packbf2(a.x, a.y);
}

static __device__ __forceinline__ uint4 combine4(const float4 wvv,
                                                 const uint4 r0, const uint4 r1,
                                                 const uint4 r2, const uint4 r3) {
    uint4 pk;
    pk.x = bl1(wvv, r0.x, r1.x, r2.x, r3.x);
    pk.y = bl1(wvv, r0.y, r1.y, r2.y, r3.y);
    pk.z = bl1(wvv, r0.z, r1.z, r2.z, r3.z);
    pk.w = bl1(wvv, r0.w, r1.w, r2.w, r3.w);
    return pk;
}

// expand packed 16-B tap record -> corner weights + corner elem offsets
static __device__ __forceinline__ void rec_expand(const uint4 rec, float4& wvv, int4& iv) {
    const float2 w01 = __half22float2(*reinterpret_cast<const __half2*>(&rec.x));
    const float2 w23 = __half22float2(*reinterpret_cast<const __half2*>(&rec.y));
    wvv = make_float4(w01.x, w01.y, w23.x, w23.y);
    iv = make_int4((int)(rec.z & 0xffffu) << 7, (int)(rec.z >> 16) << 7,
                   (int)(rec.w & 0xffffu) << 7, (int)(rec.w >> 16) << 7);
}

// lgkm-only barrier: ds ops ordered, global loads stay IN FLIGHT across it
static __device__ __forceinline__ void lds_barrier() {
    asm volatile("s_waitcnt lgkmcnt(0)" ::: "memory");
    __builtin_amdgcn_s_barrier();
    asm volatile("" ::: "memory");
}

__global__ __launch_bounds__(512, 4) void dconv_k(
    const unsigned short* __restrict__ xt, const float* __restrict__ off,
    const unsigned short* __restrict__ wb, float* __restrict__ out)
{
    // LDS: 9216 (packed taps) + 2*16640*2B (cols) = 42496 B -> 2 blocks/CU
    __shared__ alignas(16) uint4 tapG[576];                   // [k][p] packed geometry
    __shared__ alignas(16) unsigned short colsS[2][16 * 520]; // [buf][c/8][64pix][8], +8el pad

    const int idx = blockIdx.x;
    const int b = idx & 7;                 // XCD-local batch
    const int ho = (idx >> 3) & 63;
    const int tid = threadIdx.x;           // 512

    // ---- packed tap geometry: 576 = 9 taps x 64 pixels, 16 B each ----
    for (int t = tid; t < 576; t += 512) {
        const int k = t >> 6, p = t & 63;
        const int oidx = ((b * 18 + 2 * k) * 64 + ho) * 64 + p;
        const float offy = off[oidx];
        const float offx = off[oidx + 4096];
        const float py = (float)(ho - 1 + (k / 3)) + offy;
        const float px = (float)(p - 1 + (k % 3)) + offx;
        const float y0f = floorf(py), x0f = floorf(px);
        const float ly = py - y0f, lx = px - x0f;
        const int y0 = (int)y0f, x0 = (int)x0f;
        const int y1 = y0 + 1, x1 = x0 + 1;
        const float fy0 = (y0 >= 0 && y0 < 64) ? (1.0f - ly) : 0.0f;
        const float fy1 = (y1 >= 0 && y1 < 64) ? ly : 0.0f;
        const float fx0 = (x0 >= 0 && x0 < 64) ? (1.0f - lx) : 0.0f;
        const float fx1 = (x1 >= 0 && x1 < 64) ? lx : 0.0f;
        const int yc0 = min(max(y0, 0), 63), yc1 = min(max(y1, 0), 63);
        const int xc0 = min(max(x0, 0), 63), xc1 = min(max(x1, 0), 63);
        const __half2 a01 = __float22half2_rn(make_float2(fy0 * fx0, fy0 * fx1));
        const __half2 a23 = __float22half2_rn(make_float2(fy1 * fx0, fy1 * fx1));
        uint4 pk;
        __builtin_memcpy(&pk.x, &a01, 4);
        __builtin_memcpy(&pk.y, &a23, 4);
        pk.z = (unsigned int)(yc0 * 64 + xc0) | ((unsigned int)(yc0 * 64 + xc1) << 16);
        pk.w = (unsigned int)(yc1 * 64 + xc0) | ((unsigned int)(yc1 * 64 + xc1) << 16);
        tapG[t] = pk;
    }
    __syncthreads();

    const int lane = tid & 63, wv = tid >> 6;   // 8 waves
    const int quad = lane >> 4, l16 = lane & 15;
    const int g = tid & 15, p0 = tid >> 4;      // gather cell: c-octet g, pixel p0 (0..31)
    const unsigned short* xb = xt + b * (64 * 64 * 128);
    const int ph = wv & 1,  cq = wv >> 1;       // wave = 32 pixels x 32 couts
    const int pbase = ph * 32;
    const int obase = cq * 32;

    floatx4 acc[4];                             // [t(pix-tile)*2 + n(cout-tile)]
    #pragma unroll
    for (int t = 0; t < 4; t++) acc[t] = (floatx4)0.0f;

    // persistent gather pipeline regs: hold tap k+1's corners during tap k
    uint4 r[2][4];
    float4 wvv[2];

    // ---- prologue: gather+combine tap 0 -> cols[0]; issue tap-1 gathers ----
    #pragma unroll
    for (int i = 0; i < 2; i++) {
        const int p = p0 + i * 32;
        float4 w0; int4 iv;
        rec_expand(tapG[p], w0, iv);            // broadcast across the 16 g-threads
        const uint4 c0 = *(const uint4*)(xb + iv.x + g * 8);
        const uint4 c1 = *(const uint4*)(xb + iv.y + g * 8);
        const uint4 c2 = *(const uint4*)(xb + iv.z + g * 8);
        const uint4 c3 = *(const uint4*)(xb + iv.w + g * 8);
        *(uint4*)&colsS[0][g * 520 + p * 8] = combine4(w0, c0, c1, c2, c3);
    }
    #pragma unroll
    for (int i = 0; i < 2; i++) {               // tap 1 gathers -> in flight
        const int p = p0 + i * 32;
        int4 iv;
        rec_expand(tapG[64 + p], wvv[i], iv);
        r[i][0] = *(const uint4*)(xb + iv.x + g * 8);
        r[i][1] = *(const uint4*)(xb + iv.y + g * 8);
        r[i][2] = *(const uint4*)(xb + iv.z + g * 8);
        r[i][3] = *(const uint4*)(xb + iv.w + g * 8);
    }
    lds_barrier();

    // ---- tap loop: one lgkm-barrier per tap, gathers span a full tap ----
    for (int k = 0; k < 9; k++) {
        const int cur = k & 1;

        // A-fragments (32-cout slice) issued first: 8 x 16B L2 loads
        const unsigned short* wk = wb + k * 16384;
        short8 a[8];                            // [q*2 + n]
        #pragma unroll
        for (int q = 0; q < 4; q++) {
            const int cgrp = q * 4 + quad;
            #pragma unroll
            for (int n = 0; n < 2; n++)
                a[q * 2 + n] = *(const short8*)(wk + (cgrp * 128 + obase + n * 16 + l16) * 8);
        }

        // combine tap k+1 (gathers issued a FULL tap ago -> arrived) + write
        if (k < 8) {
            #pragma unroll
            for (int i = 0; i < 2; i++) {
                const int p = p0 + i * 32;
                *(uint4*)&colsS[cur ^ 1][g * 520 + p * 8] =
                    combine4(wvv[i], r[i][0], r[i][1], r[i][2], r[i][3]);
            }
        }

        // issue gathers for tap k+2; they stay in flight across the barrier
        if (k < 7) {
            #pragma unroll
            for (int i = 0; i < 2; i++) {
                const int p = p0 + i * 32;
                int4 iv;
                rec_expand(tapG[(k + 2) * 64 + p], wvv[i], iv);
                r[i][0] = *(const uint4*)(xb + iv.x + g * 8);
                r[i][1] = *(const uint4*)(xb + iv.y + g * 8);
                r[i][2] = *(const uint4*)(xb + iv.z + g * 8);
                r[i][3] = *(const uint4*)(xb + iv.w + g * 8);
            }
        }

        // MFMA: 16 per wave per tap (4 k-steps x 2 pix-tiles x 2 cout-tiles)
        #pragma unroll
        for (int q = 0; q < 4; q++) {
            const int cgrp = q * 4 + quad;
            const short8 bf0 = *(const short8*)&colsS[cur][cgrp * 520 + (pbase + l16) * 8];
            const short8 bf1 = *(const short8*)&colsS[cur][cgrp * 520 + (pbase + 16 + l16) * 8];
            acc[0] = __builtin_amdgcn_mfma_f32_16x16x32_bf16(a[q * 2 + 0], bf0, acc[0], 0, 0, 0);
            acc[1] = __builtin_amdgcn_mfma_f32_16x16x32_bf16(a[q * 2 + 1], bf0, acc[1], 0, 0, 0);
            acc[2] = __builtin_amdgcn_mfma_f32_16x16x32_bf16(a[q * 2 + 0], bf1, acc[2], 0, 0, 0);
            acc[3] = __builtin_amdgcn_mfma_f32_16x16x32_bf16(a[q * 2 + 1], bf1, acc[3], 0, 0, 0);
        }

        if (k < 8) lds_barrier();
    }

    // ---- epilogue: C/D col(=pixel)=lane&15, row(=cout)=quad*4+reg; NT stores ----
    float* ob = out + b * 128 * 4096 + ho * 64;
    #pragma unroll
    for (int t = 0; t < 2; t++) {
        const int pix = pbase + t * 16 + l16;
        #pragma unroll
        for (int n = 0; n < 2; n++) {
            #pragma unroll
            for (int r2 = 0; r2 < 4; r2++) {
                __builtin_nontemporal_store(acc[t * 2 + n][r2],
                    &ob[(obase + n * 16 + quad * 4 + r2) * 4096 + pix]);
            }
        }
    }
}

extern "C" void kernel_launch(void* const* d_in, const int* in_sizes, int n_in,
                              void* d_out, int out_size, void* d_ws, size_t ws_size,
                              hipStream_t stream) {
    const float* x   = (const float*)d_in[0];   // [8][128][64][64]
    const float* off = (const float*)d_in[1];   // [8][18][64][64]
    const float* w   = (const float*)d_in[2];   // [128][128][3][3]
    float* out = (float*)d_out;                 // [8][128][64][64]

    unsigned short* xt = (unsigned short*)d_ws;          // 4,194,304 bf16 = 8 MiB
    unsigned short* wbuf = xt + 8 * 64 * 64 * 128;       // 147,456 bf16

    hipLaunchKernelGGL(prep_k,  dim3(544), dim3(256), 0, stream,
                       x, w, (unsigned int*)xt, wbuf);
    hipLaunchKernelGGL(dconv_k, dim3(512), dim3(512), 0, stream, xt, off, wbuf, out);
}

// Round 4
// 96.679 us; speedup vs baseline: 1.0487x; 1.0243x over previous
//
#include <hip/hip_runtime.h>
#include <hip/hip_bf16.h>
#include <hip/hip_fp16.h>
#include <math.h>

// B=8, CIN=COUT=128, H=W=Ho=Wo=64, K=9, stride=pad=dil=1, EPS=1e-4.
//
// Pipeline (2 launches):
//   prep_k  : blocks 0..511  -> xt[b][h][w][c] bf16 transpose, XCD-aligned
//             blocks 512..543 -> weight norm -> bf16 A-fragment order
//                                wb[k][c/8][cout][c%8]
//   dconv_k : NEW this round: 1024 blocks x 256 thr (4 waves), block =
//             32 pixels x 128 couts (half-row). Per-CU traffic on every
//             pipe is IDENTICAL to the previous 512x512 shape (weights
//             4x32KB/tap, gathers 4x32KB/tap, same LDS ops/wave), but the
//             CU now has 4 independent barrier domains of 4 waves instead
//             of 2 domains of 8 -> per-tap barrier convoys overlap across
//             blocks. Clean A/B on the barrier-serialization theory.
//             Keeps round-3 full-tap gather pipeline + lgkm-only barrier.

typedef __attribute__((ext_vector_type(8))) short short8;   // 8 bf16 = 4 VGPRs
typedef __attribute__((ext_vector_type(4))) float floatx4;
typedef __attribute__((ext_vector_type(2))) float floatx2;

static __device__ __forceinline__ unsigned int f2bf(float f) {
    unsigned int u = __float_as_uint(f);
    u += 0x7fffu + ((u >> 16) & 1u);          // round-to-nearest-even
    return u >> 16;
}
// hw v_cvt_pk_bf16_f32 pack
static __device__ __forceinline__ unsigned int packbf2(float lo, float hi) {
    __hip_bfloat162 h = __float22bfloat162_rn(make_float2(lo, hi));
    unsigned int u;
    __builtin_memcpy(&u, &h, 4);
    return u;
}
// unpack 2 bf16 (one dword) -> float2 {lo, hi}
static __device__ __forceinline__ floatx2 bf2f2(unsigned int w) {
    floatx2 r;
    r.x = __uint_as_float(w << 16);
    r.y = __uint_as_float(w & 0xffff0000u);
    return r;
}

// Fused transpose (blocks 0..511, XCD-aligned) + weight-norm (512..543)
__global__ void prep_k(const float* __restrict__ x, const float* __restrict__ w,
                       unsigned int* __restrict__ xt32, unsigned short* __restrict__ wb) {
    __shared__ float lds[128 * 65];
    const int tid = threadIdx.x;        // 256

    if (blockIdx.x < 512) {
        const int b = blockIdx.x & 7, h = (blockIdx.x >> 3) & 63;
        const float* xp = x + (b * 128 * 64 + h) * 64;
        #pragma unroll 4
        for (int i = 0; i < 32; i++) {
            const int c = i * 4 + (tid >> 6);
            const int ww = tid & 63;
            lds[c * 65 + ww] = xp[c * 4096 + ww];
        }
        __syncthreads();
        unsigned int* xo = xt32 + (b * 64 + h) * 4096;   // [b][h][w][c/2]
        #pragma unroll 4
        for (int i = 0; i < 16; i++) {
            const int flat2 = i * 256 + tid;             // w*64 + cpair
            const int ww = flat2 >> 6, cp = flat2 & 63;
            xo[flat2] = packbf2(lds[(2 * cp) * 65 + ww], lds[(2 * cp + 1) * 65 + ww]);
        }
    } else {
        // weight norm: wave per cout o; lane holds c=2*lane, 2*lane+1
        const int o = (blockIdx.x - 512) * 4 + (tid >> 6);
        const int lane = tid & 63;
        const float* wo = w + o * 1152;                  // [c][k]
        float v[18];
        #pragma unroll
        for (int i = 0; i < 18; i++) v[i] = wo[lane * 18 + i];
        float s[9];
        #pragma unroll
        for (int k = 0; k < 9; k++) s[k] = v[k] * v[k] + v[9 + k] * v[9 + k];
        #pragma unroll
        for (int d = 32; d >= 1; d >>= 1) {
            #pragma unroll
            for (int k = 0; k < 9; k++) s[k] += __shfl_xor(s[k], d, 64);
        }
        const int c0 = 2 * lane, c1 = c0 + 1;
        #pragma unroll
        for (int k = 0; k < 9; k++) {
            const float inv = 1.0f / (3.0f * sqrtf(s[k] + 0.0128f));   // 128*EPS
            wb[((k * 16 + (c0 >> 3)) * 128 + o) * 8 + (c0 & 7)] = (unsigned short)f2bf(v[k] * inv);
            wb[((k * 16 + (c1 >> 3)) * 128 + o) * 8 + (c1 & 7)] = (unsigned short)f2bf(v[9 + k] * inv);
        }
    }
}

// packed-fp32 bilinear blend of one bf16 pair (dword) from 4 corners
static __device__ __forceinline__ unsigned int bl1(const float4 w,
                                                   unsigned int r0, unsigned int r1,
                                                   unsigned int r2, unsigned int r3) {
    floatx2 a = bf2f2(r0) * w.x;
    a += bf2f2(r1) * w.y;
    a += bf2f2(r2) * w.z;
    a += bf2f2(r3) * w.w;
    return packbf2(a.x, a.y);
}

static __device__ __forceinline__ uint4 combine4(const float4 wvv,
                                                 const uint4 r0, const uint4 r1,
                                                 const uint4 r2, const uint4 r3) {
    uint4 pk;
    pk.x = bl1(wvv, r0.x, r1.x, r2.x, r3.x);
    pk.y = bl1(wvv, r0.y, r1.y, r2.y, r3.y);
    pk.z = bl1(wvv, r0.z, r1.z, r2.z, r3.z);
    pk.w = bl1(wvv, r0.w, r1.w, r2.w, r3.w);
    return pk;
}

// expand packed 16-B tap record -> corner weights + corner elem offsets
static __device__ __forceinline__ void rec_expand(const uint4 rec, float4& wvv, int4& iv) {
    const float2 w01 = __half22float2(*reinterpret_cast<const __half2*>(&rec.x));
    const float2 w23 = __half22float2(*reinterpret_cast<const __half2*>(&rec.y));
    wvv = make_float4(w01.x, w01.y, w23.x, w23.y);
    iv = make_int4((int)(rec.z & 0xffffu) << 7, (int)(rec.z >> 16) << 7,
                   (int)(rec.w & 0xffffu) << 7, (int)(rec.w >> 16) << 7);
}

// lgkm-only barrier: ds ops ordered, global loads stay IN FLIGHT across it
static __device__ __forceinline__ void lds_barrier() {
    asm volatile("s_waitcnt lgkmcnt(0)" ::: "memory");
    __builtin_amdgcn_s_barrier();
    asm volatile("" ::: "memory");
}

__global__ __launch_bounds__(256, 4) void dconv_k(
    const unsigned short* __restrict__ xt, const float* __restrict__ off,
    const unsigned short* __restrict__ wb, float* __restrict__ out)
{
    // LDS: 4608 (packed taps) + 2*8448*2B... = 4608 + 16896 = 21504 B
    __shared__ alignas(16) uint4 tapG[288];                   // [k][p] packed geometry
    __shared__ alignas(16) unsigned short colsS[2][16 * 264]; // [buf][c/8][32pix][8], +8el pad

    const int idx = blockIdx.x;
    const int b = idx & 7;                 // XCD-local batch
    const int half = (idx >> 3) & 1;       // pixel half-row
    const int ho = (idx >> 4) & 63;
    const int tid = threadIdx.x;           // 256
    const int wbase = half * 32;

    // ---- packed tap geometry: 288 = 9 taps x 32 pixels, 16 B each ----
    for (int t = tid; t < 288; t += 256) {
        const int k = t >> 5, p = t & 31;
        const int wg = wbase + p;
        const int oidx = ((b * 18 + 2 * k) * 64 + ho) * 64 + wg;
        const float offy = off[oidx];
        const float offx = off[oidx + 4096];
        const float py = (float)(ho - 1 + (k / 3)) + offy;
        const float px = (float)(wg - 1 + (k % 3)) + offx;
        const float y0f = floorf(py), x0f = floorf(px);
        const float ly = py - y0f, lx = px - x0f;
        const int y0 = (int)y0f, x0 = (int)x0f;
        const int y1 = y0 + 1, x1 = x0 + 1;
        const float fy0 = (y0 >= 0 && y0 < 64) ? (1.0f - ly) : 0.0f;
        const float fy1 = (y1 >= 0 && y1 < 64) ? ly : 0.0f;
        const float fx0 = (x0 >= 0 && x0 < 64) ? (1.0f - lx) : 0.0f;
        const float fx1 = (x1 >= 0 && x1 < 64) ? lx : 0.0f;
        const int yc0 = min(max(y0, 0), 63), yc1 = min(max(y1, 0), 63);
        const int xc0 = min(max(x0, 0), 63), xc1 = min(max(x1, 0), 63);
        const __half2 a01 = __float22half2_rn(make_float2(fy0 * fx0, fy0 * fx1));
        const __half2 a23 = __float22half2_rn(make_float2(fy1 * fx0, fy1 * fx1));
        uint4 pk;
        __builtin_memcpy(&pk.x, &a01, 4);
        __builtin_memcpy(&pk.y, &a23, 4);
        pk.z = (unsigned int)(yc0 * 64 + xc0) | ((unsigned int)(yc0 * 64 + xc1) << 16);
        pk.w = (unsigned int)(yc1 * 64 + xc0) | ((unsigned int)(yc1 * 64 + xc1) << 16);
        tapG[t] = pk;
    }
    __syncthreads();

    const int lane = tid & 63, wv = tid >> 6;   // 4 waves
    const int quad = lane >> 4, l16 = lane & 15;
    const int g = tid & 15, p0 = tid >> 4;      // gather cell: c-octet g, pixel p0 (0..15)
    const unsigned short* xb = xt + b * (64 * 64 * 128);
    const int obase = wv * 32;                  // wave = 32 pixels x 32 couts

    floatx4 acc[4];                             // [t(pix-tile)*2 + n(cout-tile)]
    #pragma unroll
    for (int t = 0; t < 4; t++) acc[t] = (floatx4)0.0f;

    // persistent gather pipeline regs: hold tap k+1's corners during tap k
    uint4 r[2][4];
    float4 wvv[2];

    // ---- prologue: gather+combine tap 0 -> cols[0]; issue tap-1 gathers ----
    #pragma unroll
    for (int i = 0; i < 2; i++) {
        const int p = p0 + i * 16;
        float4 w0; int4 iv;
        rec_expand(tapG[p], w0, iv);            // broadcast across the 16 g-threads
        const uint4 c0 = *(const uint4*)(xb + iv.x + g * 8);
        const uint4 c1 = *(const uint4*)(xb + iv.y + g * 8);
        const uint4 c2 = *(const uint4*)(xb + iv.z + g * 8);
        const uint4 c3 = *(const uint4*)(xb + iv.w + g * 8);
        *(uint4*)&colsS[0][g * 264 + p * 8] = combine4(w0, c0, c1, c2, c3);
    }
    #pragma unroll
    for (int i = 0; i < 2; i++) {               // tap 1 gathers -> in flight
        const int p = p0 + i * 16;
        int4 iv;
        rec_expand(tapG[32 + p], wvv[i], iv);
        r[i][0] = *(const uint4*)(xb + iv.x + g * 8);
        r[i][1] = *(const uint4*)(xb + iv.y + g * 8);
        r[i][2] = *(const uint4*)(xb + iv.z + g * 8);
        r[i][3] = *(const uint4*)(xb + iv.w + g * 8);
    }
    lds_barrier();

    // ---- tap loop: one lgkm-barrier per tap, gathers span a full tap ----
    for (int k = 0; k < 9; k++) {
        const int cur = k & 1;

        // A-fragments (32-cout slice) issued first: 8 x 16B L2 loads
        const unsigned short* wk = wb + k * 16384;
        short8 a[8];                            // [q*2 + n]
        #pragma unroll
        for (int q = 0; q < 4; q++) {
            const int cgrp = q * 4 + quad;
            #pragma unroll
            for (int n = 0; n < 2; n++)
                a[q * 2 + n] = *(const short8*)(wk + (cgrp * 128 + obase + n * 16 + l16) * 8);
        }

        // combine tap k+1 (gathers issued a FULL tap ago -> arrived) + write
        if (k < 8) {
            #pragma unroll
            for (int i = 0; i < 2; i++) {
                const int p = p0 + i * 16;
                *(uint4*)&colsS[cur ^ 1][g * 264 + p * 8] =
                    combine4(wvv[i], r[i][0], r[i][1], r[i][2], r[i][3]);
            }
        }

        // issue gathers for tap k+2; they stay in flight across the barrier
        if (k < 7) {
            #pragma unroll
            for (int i = 0; i < 2; i++) {
                const int p = p0 + i * 16;
                int4 iv;
                rec_expand(tapG[(k + 2) * 32 + p], wvv[i], iv);
                r[i][0] = *(const uint4*)(xb + iv.x + g * 8);
                r[i][1] = *(const uint4*)(xb + iv.y + g * 8);
                r[i][2] = *(const uint4*)(xb + iv.z + g * 8);
                r[i][3] = *(const uint4*)(xb + iv.w + g * 8);
            }
        }

        // MFMA: 16 per wave per tap (4 k-steps x 2 pix-tiles x 2 cout-tiles)
        #pragma unroll
        for (int q = 0; q < 4; q++) {
            const int cgrp = q * 4 + quad;
            const short8 bf0 = *(const short8*)&colsS[cur][cgrp * 264 + l16 * 8];
            const short8 bf1 = *(const short8*)&colsS[cur][cgrp * 264 + (16 + l16) * 8];
            acc[0] = __builtin_amdgcn_mfma_f32_16x16x32_bf16(a[q * 2 + 0], bf0, acc[0], 0, 0, 0);
            acc[1] = __builtin_amdgcn_mfma_f32_16x16x32_bf16(a[q * 2 + 1], bf0, acc[1], 0, 0, 0);
            acc[2] = __builtin_amdgcn_mfma_f32_16x16x32_bf16(a[q * 2 + 0], bf1, acc[2], 0, 0, 0);
            acc[3] = __builtin_amdgcn_mfma_f32_16x16x32_bf16(a[q * 2 + 1], bf1, acc[3], 0, 0, 0);
        }

        if (k < 8) lds_barrier();
    }

    // ---- epilogue: C/D col(=pixel)=lane&15, row(=cout)=quad*4+reg; NT stores ----
    float* ob = out + b * 128 * 4096 + ho * 64 + wbase;
    #pragma unroll
    for (int t = 0; t < 2; t++) {
        const int pix = t * 16 + l16;
        #pragma unroll
        for (int n = 0; n < 2; n++) {
            #pragma unroll
            for (int r2 = 0; r2 < 4; r2++) {
                __builtin_nontemporal_store(acc[t * 2 + n][r2],
                    &ob[(obase + n * 16 + quad * 4 + r2) * 4096 + pix]);
            }
        }
    }
}

extern "C" void kernel_launch(void* const* d_in, const int* in_sizes, int n_in,
                              void* d_out, int out_size, void* d_ws, size_t ws_size,
                              hipStream_t stream) {
    const float* x   = (const float*)d_in[0];   // [8][128][64][64]
    const float* off = (const float*)d_in[1];   // [8][18][64][64]
    const float* w   = (const float*)d_in[2];   // [128][128][3][3]
    float* out = (float*)d_out;                 // [8][128][64][64]

    unsigned short* xt = (unsigned short*)d_ws;          // 4,194,304 bf16 = 8 MiB
    unsigned short* wbuf = xt + 8 * 64 * 64 * 128;       // 147,456 bf16

    hipLaunchKernelGGL(prep_k,  dim3(544), dim3(256), 0, stream,
                       x, w, (unsigned int*)xt, wbuf);
    hipLaunchKernelGGL(dconv_k, dim3(1024), dim3(256), 0, stream, xt, off, wbuf, out);
}